// Round 5
// baseline (94.795 us; speedup 1.0000x reference)
//
#include <hip/hip_runtime.h>

// Decoder: 2-layer LSTM (H=32) + MLP (96), B=16384, 25 steps. MFMA, weights in
// VGPR fragments. R5: ET=32 -> grid 512 = 2 blocks/CU (independent barrier
// domains hide phase drains); output written directly from C-fragments
// (float4, 64B-line coalesced); stage buffer deleted. Inputs/outputs f32 (R2).

#define PRED 25
#define BATCH 16384
#define ET    32
#define XROW  192   // xh row (u16): 0..95 x/curr, 96..127 h0_A, 128..159 h0_B
#define HROW  128   // hh row: 0..31 h0, 32..63 h1_A, 64..95 h1_B
#define LROW  64    // h1lo row

typedef unsigned short u16;
typedef unsigned int   u32;
typedef __attribute__((ext_vector_type(8))) short bf16x8;
typedef __attribute__((ext_vector_type(4))) float f32x4;

__device__ __forceinline__ float fast_rcp(float x){ return __builtin_amdgcn_rcpf(x); }
__device__ __forceinline__ float sigm(float x){ return fast_rcp(1.0f + __expf(-x)); }
__device__ __forceinline__ float tanh_(float x){ return 1.0f - 2.0f*fast_rcp(__expf(2.0f*x) + 1.0f); }
__device__ __forceinline__ u16 f2b(float f){
  u32 i = __float_as_uint(f);
  i += 0x7FFFu + ((i >> 16) & 1u);
  return (u16)(i >> 16);
}
__device__ __forceinline__ float b2f(u16 u){ return __uint_as_float(((u32)u) << 16); }

struct __align__(16) SM {
  u16 xh[ET*XROW];
  u16 hh[ET*HROW];
  u16 h1lo[ET*LROW];
};

__device__ __forceinline__ int swx(int e, int k){ return e*XROW + (k ^ ((e&7)<<3)); }
__device__ __forceinline__ int swh(int e, int k){ return e*HROW + (k ^ ((e&7)<<3)); }
__device__ __forceinline__ int swl(int e, int k){ return e*LROW + (k ^ ((e&7)<<3)); }

__device__ __forceinline__ bf16x8 pack8(float4 f0, float4 f1){
  union { bf16x8 v; u16 u8[8]; } fr;
  fr.u8[0]=f2b(f0.x); fr.u8[1]=f2b(f0.y); fr.u8[2]=f2b(f0.z); fr.u8[3]=f2b(f0.w);
  fr.u8[4]=f2b(f1.x); fr.u8[5]=f2b(f1.y); fr.u8[6]=f2b(f1.z); fr.u8[7]=f2b(f1.w);
  return fr.v;
}

extern "C" __global__ __launch_bounds__(512, 4)
void decoder_kernel(const float* __restrict__ obs,  const float* __restrict__ lat,
                    const float* __restrict__ Wfc,  const float* __restrict__ bfc,
                    const float* __restrict__ Wih0, const float* __restrict__ Whh0,
                    const float* __restrict__ bih0, const float* __restrict__ bhh0,
                    const float* __restrict__ Wih1, const float* __restrict__ Whh1,
                    const float* __restrict__ bih1, const float* __restrict__ bhh1,
                    const float* __restrict__ Wmlp, const float* __restrict__ bmlp,
                    float* __restrict__ out)
{
  __shared__ SM sm;
  const int tid = threadIdx.x;
  const int ebase = blockIdx.x * ET;
  const int w  = tid >> 6;        // wave 0..7
  const int l  = tid & 63;
  const int lr = l & 15;          // row/col within 16-tile
  const int kq = l >> 4;          // k-quad 0..3
  const int nw = w & 1;           // n-tile (e block 0..1)
  const int mg = w >> 1;          // m-group 0..3 (2 m-tiles each)
  const int e_ln = nw*16 + lr;    // lane's e column

  // ---- one-time LDS init: x = obs[15] (bf16), h_init -> h0/h1 parity 0 ----
  {
    int e = tid >> 4, c6 = (tid & 15)*6;
    const float* src = obs + ((size_t)(15*BATCH) + ebase + e)*96 + c6;
    float2 a = *(const float2*)(src);
    float2 b = *(const float2*)(src+2);
    float2 c = *(const float2*)(src+4);
    float v[6] = {a.x,a.y,b.x,b.y,c.x,c.y};
    #pragma unroll
    for (int j = 0; j < 3; ++j){
      u32 pk = (u32)f2b(v[2*j]) | ((u32)f2b(v[2*j+1]) << 16);
      *(u32*)&sm.xh[swx(e, c6 + 2*j)] = pk;
    }
  }
  {
    int u = tid & 31, eb = (tid >> 5)*2;
    const float* wf = Wfc + u*16;
    float bb = bfc[u];
    #pragma unroll
    for (int e2 = 0; e2 < 2; ++e2){
      int e = eb + e2;
      const float* lp = lat + (size_t)(ebase + e)*16;
      float a = bb;
      #pragma unroll
      for (int j = 0; j < 16; ++j) a = fmaf(wf[j], lp[j], a);
      u16 hb = f2b(a);
      sm.xh[swx(e, 96 + u)] = hb;   // h0 parity 0
      sm.hh[swh(e, 32 + u)] = hb;   // h1 parity 0
    }
  }

  // ---- preload weight A-fragments (step-invariant, registers) ----
  bf16x8 aw0[2][4];                 // GEMM0: 2 m-tiles x 4 k-chunks
  #pragma unroll
  for (int j = 0; j < 2; ++j){
    int vg = (mg*2 + j)*16 + lr;
    int g  = (vg & 3)*32 + (vg >> 2);   // gate-permuted row
    #pragma unroll
    for (int c = 0; c < 4; ++c){
      int k = c*32 + kq*8;
      const float* src = (k < 96) ? (Wih0 + g*96 + k) : (Whh0 + g*32 + (k - 96));
      aw0[j][c] = pack8(*(const float4*)src, *(const float4*)(src+4));
    }
  }
  bf16x8 aw1[2][2];                 // GEMM1: K=64
  #pragma unroll
  for (int j = 0; j < 2; ++j){
    int vg = (mg*2 + j)*16 + lr;
    int g  = (vg & 3)*32 + (vg >> 2);
    #pragma unroll
    for (int c = 0; c < 2; ++c){
      int k = c*32 + kq*8;
      const float* src = (k < 32) ? (Wih1 + g*32 + k) : (Whh1 + g*32 + (k - 32));
      aw1[j][c] = pack8(*(const float4*)src, *(const float4*)(src+4));
    }
  }
  // MLP tiles: waves 0-3 own {mg, mg+4} (mg=w>>1 in 0..1), waves 4-7 own {w>>1}
  const int mt0 = w >> 1;           // always valid
  const int mt1 = (w >> 1) + 4;     // valid only for w<4
  bf16x8 awm0, awm1;
  {
    int o = mt0*16 + lr;
    const float* src = Wmlp + o*32 + kq*8;
    awm0 = pack8(*(const float4*)src, *(const float4*)(src+4));
  }
  if (w < 4){
    int o = mt1*16 + lr;
    const float* src = Wmlp + o*32 + kq*8;
    awm1 = pack8(*(const float4*)src, *(const float4*)(src+4));
  }

  // ---- biases (C-frag rows = kq*4 + r) ----
  f32x4 bias0v[2], bias1v[2];
  #pragma unroll
  for (int j = 0; j < 2; ++j){
    int u = (mg*2 + j)*4 + kq;
    #pragma unroll
    for (int r = 0; r < 4; ++r){
      int g = r*32 + u;
      bias0v[j][r] = bih0[g] + bhh0[g];
      bias1v[j][r] = bih1[g] + bhh1[g];
    }
  }
  f32x4 biasm0, biasm1;
  #pragma unroll
  for (int r = 0; r < 4; ++r) biasm0[r] = bmlp[mt0*16 + kq*4 + r];
  if (w < 4){
    #pragma unroll
    for (int r = 0; r < 4; ++r) biasm1[r] = bmlp[mt1*16 + kq*4 + r];
  }

  float c0s[2] = {0.f, 0.f};
  float c1s[2] = {0.f, 0.f};

  __syncthreads();

  for (int t = 0; t < PRED; ++t){
    const int p = t & 1;
    // ---- P1: GEMM0 gates0[128vg x 32e] = W0 * [x;h0] ----
    bf16x8 bx0 = *(const bf16x8*)&sm.xh[swx(e_ln, 0*32 + kq*8)];
    bf16x8 bx1 = *(const bf16x8*)&sm.xh[swx(e_ln, 1*32 + kq*8)];
    bf16x8 bx2 = *(const bf16x8*)&sm.xh[swx(e_ln, 2*32 + kq*8)];
    bf16x8 bx3 = *(const bf16x8*)&sm.xh[swx(e_ln, 96 + 32*p + kq*8)];
    f32x4 g0[2];
    #pragma unroll
    for (int j = 0; j < 2; ++j){
      f32x4 a = bias0v[j];
      a = __builtin_amdgcn_mfma_f32_16x16x32_bf16(aw0[j][0], bx0, a, 0, 0, 0);
      a = __builtin_amdgcn_mfma_f32_16x16x32_bf16(aw0[j][1], bx1, a, 0, 0, 0);
      a = __builtin_amdgcn_mfma_f32_16x16x32_bf16(aw0[j][2], bx2, a, 0, 0, 0);
      a = __builtin_amdgcn_mfma_f32_16x16x32_bf16(aw0[j][3], bx3, a, 0, 0, 0);
      g0[j] = a;
    }
    // ---- LSTM0 activation; h0 -> parity p^1 + hh rows 0..31 ----
    #pragma unroll
    for (int j = 0; j < 2; ++j){
      float ig = sigm(g0[j][0]);
      float fg = sigm(g0[j][1]);
      float gg = tanh_(g0[j][2]);
      float og = sigm(g0[j][3]);
      float cn = fmaf(fg, c0s[j], ig*gg);
      c0s[j] = cn;
      u16 hb = f2b(og * tanh_(cn));
      int u = (mg*2 + j)*4 + kq;
      sm.xh[swx(e_ln, 96 + 32*(p^1) + u)] = hb;
      sm.hh[swh(e_ln, u)] = hb;
    }
    __syncthreads();   // B2: h0 visible
    // ---- P3: GEMM1 gates1 = W1 * [h0_new; h1_prev] ----
    bf16x8 bh0 = *(const bf16x8*)&sm.hh[swh(e_ln, kq*8)];
    bf16x8 bh1 = *(const bf16x8*)&sm.hh[swh(e_ln, 32 + 32*p + kq*8)];
    f32x4 g1[2];
    #pragma unroll
    for (int j = 0; j < 2; ++j){
      f32x4 a = bias1v[j];
      a = __builtin_amdgcn_mfma_f32_16x16x32_bf16(aw1[j][0], bh0, a, 0, 0, 0);
      a = __builtin_amdgcn_mfma_f32_16x16x32_bf16(aw1[j][1], bh1, a, 0, 0, 0);
      g1[j] = a;
    }
    #pragma unroll
    for (int j = 0; j < 2; ++j){
      float ig = sigm(g1[j][0]);
      float fg = sigm(g1[j][1]);
      float gg = tanh_(g1[j][2]);
      float og = sigm(g1[j][3]);
      float cn = fmaf(fg, c1s[j], ig*gg);
      c1s[j] = cn;
      float h1 = og * tanh_(cn);
      u16 hi = f2b(h1);
      u16 lo = f2b(h1 - b2f(hi));
      int u = (mg*2 + j)*4 + kq;
      sm.hh[swh(e_ln, 32 + 32*(p^1) + u)] = hi;   // h1_new
      sm.h1lo[swl(e_ln, u)] = lo;                 // residual for MLP split
    }
    __syncthreads();   // B4: h1 visible
    // ---- P4: MLP curr = Wm*(h1_hi + h1_lo) + b; direct f32x4 global store ----
    bf16x8 bmh = *(const bf16x8*)&sm.hh[swh(e_ln, 32 + 32*(p^1) + kq*8)];
    bf16x8 bml = *(const bf16x8*)&sm.h1lo[swl(e_ln, kq*8)];
    float* outb = out + (size_t)t*BATCH*96 + (size_t)(ebase + e_ln)*96;
    {
      f32x4 a = biasm0;
      a = __builtin_amdgcn_mfma_f32_16x16x32_bf16(awm0, bmh, a, 0, 0, 0);
      a = __builtin_amdgcn_mfma_f32_16x16x32_bf16(awm0, bml, a, 0, 0, 0);
      int o0 = mt0*16 + kq*4;
      u32 pk01 = (u32)f2b(a[0]) | ((u32)f2b(a[1]) << 16);
      u32 pk23 = (u32)f2b(a[2]) | ((u32)f2b(a[3]) << 16);
      *(u32*)&sm.xh[swx(e_ln, o0)]     = pk01;      // bf16 feedback (next x)
      *(u32*)&sm.xh[swx(e_ln, o0 + 2)] = pk23;
      *(f32x4*)(outb + o0) = a;                     // exact f32 output
    }
    if (w < 4){
      f32x4 a = biasm1;
      a = __builtin_amdgcn_mfma_f32_16x16x32_bf16(awm1, bmh, a, 0, 0, 0);
      a = __builtin_amdgcn_mfma_f32_16x16x32_bf16(awm1, bml, a, 0, 0, 0);
      int o0 = mt1*16 + kq*4;
      u32 pk01 = (u32)f2b(a[0]) | ((u32)f2b(a[1]) << 16);
      u32 pk23 = (u32)f2b(a[2]) | ((u32)f2b(a[3]) << 16);
      *(u32*)&sm.xh[swx(e_ln, o0)]     = pk01;
      *(u32*)&sm.xh[swx(e_ln, o0 + 2)] = pk23;
      *(f32x4*)(outb + o0) = a;
    }
    __syncthreads();   // B5: curr (next x) visible for P1(t+1)
  }
}

extern "C" void kernel_launch(void* const* d_in, const int* in_sizes, int n_in,
                              void* d_out, int out_size, void* d_ws, size_t ws_size,
                              hipStream_t stream){
  decoder_kernel<<<dim3(BATCH/ET), dim3(512), 0, stream>>>(
      (const float*)d_in[0],  (const float*)d_in[1],
      (const float*)d_in[3],  (const float*)d_in[4],
      (const float*)d_in[5],  (const float*)d_in[6],
      (const float*)d_in[7],  (const float*)d_in[8],
      (const float*)d_in[9],  (const float*)d_in[10],
      (const float*)d_in[11], (const float*)d_in[12],
      (const float*)d_in[13], (const float*)d_in[14],
      (float*)d_out);
}

// Round 6
// 80.564 us; speedup vs baseline: 1.1766x; 1.1766x over previous
//
#include <hip/hip_runtime.h>

// Decoder: 2-layer LSTM (H=32) + MLP (96), B=16384, 25 steps. MFMA, weights in
// VGPR fragments. R6: kernel time == per-block serial latency (R4/R5 evidence),
// so: 2-wave blocks (barrier skew ~0), ET=16, grid=1024 (4 blocks/CU, all
// resident at 2 waves/SIMD), global store moved AFTER B5 (ack drains at next
// step's B2, off the critical path). Inputs/outputs f32 (R2-proved).

#define PRED 25
#define BATCH 16384
#define ET    16
#define XROW  192   // xh row (u16): 0..95 x/curr, 96..127 h0_A, 128..159 h0_B
#define HROW  128   // hh row: 0..31 h0, 32..63 h1_A, 64..95 h1_B
#define LROW  64    // h1lo row

typedef unsigned short u16;
typedef unsigned int   u32;
typedef __attribute__((ext_vector_type(8))) short bf16x8;
typedef __attribute__((ext_vector_type(4))) float f32x4;

__device__ __forceinline__ float fast_rcp(float x){ return __builtin_amdgcn_rcpf(x); }
__device__ __forceinline__ float sigm(float x){ return fast_rcp(1.0f + __expf(-x)); }
__device__ __forceinline__ float tanh_(float x){ return 1.0f - 2.0f*fast_rcp(__expf(2.0f*x) + 1.0f); }
__device__ __forceinline__ u16 f2b(float f){
  u32 i = __float_as_uint(f);
  i += 0x7FFFu + ((i >> 16) & 1u);
  return (u16)(i >> 16);
}
__device__ __forceinline__ float b2f(u16 u){ return __uint_as_float(((u32)u) << 16); }

struct __align__(16) SM {
  u16 xh[ET*XROW];
  u16 hh[ET*HROW];
  u16 h1lo[ET*LROW];
};

__device__ __forceinline__ int swx(int e, int k){ return e*XROW + (k ^ ((e&7)<<3)); }
__device__ __forceinline__ int swh(int e, int k){ return e*HROW + (k ^ ((e&7)<<3)); }
__device__ __forceinline__ int swl(int e, int k){ return e*LROW + (k ^ ((e&7)<<3)); }

__device__ __forceinline__ bf16x8 pack8(float4 f0, float4 f1){
  union { bf16x8 v; u16 u8[8]; } fr;
  fr.u8[0]=f2b(f0.x); fr.u8[1]=f2b(f0.y); fr.u8[2]=f2b(f0.z); fr.u8[3]=f2b(f0.w);
  fr.u8[4]=f2b(f1.x); fr.u8[5]=f2b(f1.y); fr.u8[6]=f2b(f1.z); fr.u8[7]=f2b(f1.w);
  return fr.v;
}

extern "C" __global__ __launch_bounds__(128, 2)
void decoder_kernel(const float* __restrict__ obs,  const float* __restrict__ lat,
                    const float* __restrict__ Wfc,  const float* __restrict__ bfc,
                    const float* __restrict__ Wih0, const float* __restrict__ Whh0,
                    const float* __restrict__ bih0, const float* __restrict__ bhh0,
                    const float* __restrict__ Wih1, const float* __restrict__ Whh1,
                    const float* __restrict__ bih1, const float* __restrict__ bhh1,
                    const float* __restrict__ Wmlp, const float* __restrict__ bmlp,
                    float* __restrict__ out)
{
  __shared__ SM sm;
  const int tid = threadIdx.x;
  const int ebase = blockIdx.x * ET;
  const int mh = tid >> 6;        // wave 0..1 = m-half
  const int l  = tid & 63;
  const int lr = l & 15;          // row/col within 16-tile; also lane's e
  const int kq = l >> 4;          // k-quad 0..3
  const int e_ln = lr;            // single e-tile per block

  // ---- one-time LDS init: x = obs[15] (bf16), h_init -> h0/h1 parity 0 ----
  {
    int e = tid >> 3, c8 = (tid & 7)*12;
    const float* src = obs + ((size_t)(15*BATCH) + ebase + e)*96 + c8;
    float4 a = *(const float4*)(src);
    float4 b = *(const float4*)(src+4);
    float4 c = *(const float4*)(src+8);
    float v[12] = {a.x,a.y,a.z,a.w,b.x,b.y,b.z,b.w,c.x,c.y,c.z,c.w};
    #pragma unroll
    for (int j = 0; j < 6; ++j){
      u32 pk = (u32)f2b(v[2*j]) | ((u32)f2b(v[2*j+1]) << 16);
      *(u32*)&sm.xh[swx(e, c8 + 2*j)] = pk;
    }
  }
  {
    int u = tid & 31, eb = (tid >> 5)*4;
    const float* wf = Wfc + u*16;
    float bb = bfc[u];
    #pragma unroll
    for (int e4 = 0; e4 < 4; ++e4){
      int e = eb + e4;
      const float* lp = lat + (size_t)(ebase + e)*16;
      float a = bb;
      #pragma unroll
      for (int j = 0; j < 16; ++j) a = fmaf(wf[j], lp[j], a);
      u16 hb = f2b(a);
      sm.xh[swx(e, 96 + u)] = hb;   // h0 parity 0
      sm.hh[swh(e, 32 + u)] = hb;   // h1 parity 0
    }
  }

  // ---- preload weight A-fragments (step-invariant, registers) ----
  bf16x8 aw0[4][4];                 // GEMM0: 4 m-tiles x 4 k-chunks
  #pragma unroll
  for (int i = 0; i < 4; ++i){
    int vg = (mh*4 + i)*16 + lr;
    int g  = (vg & 3)*32 + (vg >> 2);   // gate-permuted row
    #pragma unroll
    for (int c = 0; c < 4; ++c){
      int k = c*32 + kq*8;
      const float* src = (k < 96) ? (Wih0 + g*96 + k) : (Whh0 + g*32 + (k - 96));
      aw0[i][c] = pack8(*(const float4*)src, *(const float4*)(src+4));
    }
  }
  bf16x8 aw1[4][2];                 // GEMM1: K=64
  #pragma unroll
  for (int i = 0; i < 4; ++i){
    int vg = (mh*4 + i)*16 + lr;
    int g  = (vg & 3)*32 + (vg >> 2);
    #pragma unroll
    for (int c = 0; c < 2; ++c){
      int k = c*32 + kq*8;
      const float* src = (k < 32) ? (Wih1 + g*32 + k) : (Whh1 + g*32 + (k - 32));
      aw1[i][c] = pack8(*(const float4*)src, *(const float4*)(src+4));
    }
  }
  bf16x8 awm[3];                    // MLP: M=96 -> 3 m-tiles per wave, K=32
  #pragma unroll
  for (int i = 0; i < 3; ++i){
    int o = (mh*3 + i)*16 + lr;
    const float* src = Wmlp + o*32 + kq*8;
    awm[i] = pack8(*(const float4*)src, *(const float4*)(src+4));
  }

  // ---- biases (C-frag rows = kq*4 + r) ----
  f32x4 bias0v[4], bias1v[4];
  #pragma unroll
  for (int i = 0; i < 4; ++i){
    int u = (mh*4 + i)*4 + kq;
    #pragma unroll
    for (int r = 0; r < 4; ++r){
      int g = r*32 + u;
      bias0v[i][r] = bih0[g] + bhh0[g];
      bias1v[i][r] = bih1[g] + bhh1[g];
    }
  }
  f32x4 biasmv[3];
  #pragma unroll
  for (int i = 0; i < 3; ++i){
    int o0 = (mh*3 + i)*16 + kq*4;
    #pragma unroll
    for (int r = 0; r < 4; ++r) biasmv[i][r] = bmlp[o0 + r];
  }

  float c0s[4] = {0.f,0.f,0.f,0.f};
  float c1s[4] = {0.f,0.f,0.f,0.f};

  __syncthreads();

  f32x4 am[3];          // MLP result, stored to global AFTER B5
  bool have_out = false;
  float* outb = nullptr;

  for (int t = 0; t < PRED; ++t){
    const int p = t & 1;
    // ---- P1: GEMM0 gates0[128vg x 16e] = W0 * [x;h0] ----
    bf16x8 bx0 = *(const bf16x8*)&sm.xh[swx(e_ln, 0*32 + kq*8)];
    bf16x8 bx1 = *(const bf16x8*)&sm.xh[swx(e_ln, 1*32 + kq*8)];
    bf16x8 bx2 = *(const bf16x8*)&sm.xh[swx(e_ln, 2*32 + kq*8)];
    bf16x8 bx3 = *(const bf16x8*)&sm.xh[swx(e_ln, 96 + 32*p + kq*8)];
    f32x4 g0[4];
    #pragma unroll
    for (int i = 0; i < 4; ++i){
      f32x4 a = bias0v[i];
      a = __builtin_amdgcn_mfma_f32_16x16x32_bf16(aw0[i][0], bx0, a, 0, 0, 0);
      a = __builtin_amdgcn_mfma_f32_16x16x32_bf16(aw0[i][1], bx1, a, 0, 0, 0);
      a = __builtin_amdgcn_mfma_f32_16x16x32_bf16(aw0[i][2], bx2, a, 0, 0, 0);
      a = __builtin_amdgcn_mfma_f32_16x16x32_bf16(aw0[i][3], bx3, a, 0, 0, 0);
      g0[i] = a;
    }
    // ---- LSTM0 activation; h0 -> parity p^1 + hh rows 0..31 ----
    #pragma unroll
    for (int i = 0; i < 4; ++i){
      float ig = sigm(g0[i][0]);
      float fg = sigm(g0[i][1]);
      float gg = tanh_(g0[i][2]);
      float og = sigm(g0[i][3]);
      float cn = fmaf(fg, c0s[i], ig*gg);
      c0s[i] = cn;
      u16 hb = f2b(og * tanh_(cn));
      int u = (mh*4 + i)*4 + kq;
      sm.xh[swx(e_ln, 96 + 32*(p^1) + u)] = hb;
      sm.hh[swh(e_ln, u)] = hb;
    }
    __syncthreads();   // B2: h0 visible (also drains prev step's global store)
    // ---- P3: GEMM1 gates1 = W1 * [h0_new; h1_prev] ----
    bf16x8 bh0 = *(const bf16x8*)&sm.hh[swh(e_ln, kq*8)];
    bf16x8 bh1 = *(const bf16x8*)&sm.hh[swh(e_ln, 32 + 32*p + kq*8)];
    f32x4 g1[4];
    #pragma unroll
    for (int i = 0; i < 4; ++i){
      f32x4 a = bias1v[i];
      a = __builtin_amdgcn_mfma_f32_16x16x32_bf16(aw1[i][0], bh0, a, 0, 0, 0);
      a = __builtin_amdgcn_mfma_f32_16x16x32_bf16(aw1[i][1], bh1, a, 0, 0, 0);
      g1[i] = a;
    }
    #pragma unroll
    for (int i = 0; i < 4; ++i){
      float ig = sigm(g1[i][0]);
      float fg = sigm(g1[i][1]);
      float gg = tanh_(g1[i][2]);
      float og = sigm(g1[i][3]);
      float cn = fmaf(fg, c1s[i], ig*gg);
      c1s[i] = cn;
      float h1 = og * tanh_(cn);
      u16 hi = f2b(h1);
      u16 lo = f2b(h1 - b2f(hi));
      int u = (mh*4 + i)*4 + kq;
      sm.hh[swh(e_ln, 32 + 32*(p^1) + u)] = hi;   // h1_new
      sm.h1lo[swl(e_ln, u)] = lo;                 // residual for MLP split
    }
    __syncthreads();   // B4: h1 visible
    // ---- P4: MLP curr = Wm*(h1_hi + h1_lo) + b; feedback to xh ----
    bf16x8 bmh = *(const bf16x8*)&sm.hh[swh(e_ln, 32 + 32*(p^1) + kq*8)];
    bf16x8 bml = *(const bf16x8*)&sm.h1lo[swl(e_ln, kq*8)];
    #pragma unroll
    for (int i = 0; i < 3; ++i){
      f32x4 a = biasmv[i];
      a = __builtin_amdgcn_mfma_f32_16x16x32_bf16(awm[i], bmh, a, 0, 0, 0);
      a = __builtin_amdgcn_mfma_f32_16x16x32_bf16(awm[i], bml, a, 0, 0, 0);
      am[i] = a;
      int o0 = (mh*3 + i)*16 + kq*4;
      u32 pk01 = (u32)f2b(a[0]) | ((u32)f2b(a[1]) << 16);
      u32 pk23 = (u32)f2b(a[2]) | ((u32)f2b(a[3]) << 16);
      *(u32*)&sm.xh[swx(e_ln, o0)]     = pk01;      // bf16 feedback (next x)
      *(u32*)&sm.xh[swx(e_ln, o0 + 2)] = pk23;
    }
    outb = out + (size_t)t*BATCH*96 + (size_t)(ebase + e_ln)*96;
    have_out = true;
    __syncthreads();   // B5: curr (next x) visible for P1(t+1)
    // ---- global store AFTER the barrier: ack overlaps next P1, drains at B2 ----
    #pragma unroll
    for (int i = 0; i < 3; ++i){
      int o0 = (mh*3 + i)*16 + kq*4;
      *(f32x4*)(outb + o0) = am[i];
    }
  }
  (void)have_out;
}

extern "C" void kernel_launch(void* const* d_in, const int* in_sizes, int n_in,
                              void* d_out, int out_size, void* d_ws, size_t ws_size,
                              hipStream_t stream){
  decoder_kernel<<<dim3(BATCH/ET), dim3(128), 0, stream>>>(
      (const float*)d_in[0],  (const float*)d_in[1],
      (const float*)d_in[3],  (const float*)d_in[4],
      (const float*)d_in[5],  (const float*)d_in[6],
      (const float*)d_in[7],  (const float*)d_in[8],
      (const float*)d_in[9],  (const float*)d_in[10],
      (const float*)d_in[11], (const float*)d_in[12],
      (const float*)d_in[13], (const float*)d_in[14],
      (float*)d_out);
}